// Round 2
// baseline (566.070 us; speedup 1.0000x reference)
//
#include <hip/hip_runtime.h>

#define HH 128
#define WW 128
#define HWSZ (128*128)
#define CC 64
#define OO 64
#define BB 4

// ws layout (floats):
//   off    : [B][18][H][W]   at 0        size 4*18*16384 = 1179648
//   wdef_t : [576][64]       at 1179648  size 36864
//   woff_t : [576][24]       at 1216512  size 13824 (cols 18..23 zero pad)

__global__ void k_transpose(const float* __restrict__ w_off,
                            const float* __restrict__ w_def,
                            float* __restrict__ woff_t,
                            float* __restrict__ wdef_t) {
    int i = blockIdx.x * 256 + threadIdx.x;
    if (i < 576 * 64) {
        int row = i >> 6, o = i & 63;            // row = c*9+kk
        wdef_t[i] = w_def[o * 576 + row];
    }
    int j = i - 576 * 64;
    if (j >= 0 && j < 576 * 24) {
        int row = j / 24, col = j - row * 24;    // row = c*9+r
        woff_t[j] = (col < 18) ? w_off[col * 576 + row] : 0.f;
    }
}

// 256 threads: w = tid&127, ch = tid>>7 picks c-half. Partial sums combined
// via LDS, half 0 stores clipped offsets. XCD swizzle: 512 blocks, 64/XCD,
// each XCD sees one batch's 32-channel slab (2 MB <= 4 MB L2).
__launch_bounds__(256)
__global__ void k_offconv(const float* __restrict__ x,
                          const float* __restrict__ woff_t,
                          const float* __restrict__ b_off,
                          float* __restrict__ off) {
    __shared__ float ex[128 * 18];
    int sb = (blockIdx.x & 7) * 64 + (blockIdx.x >> 3);   // bijective, 512%8==0
    int b = sb >> 7, h = sb & 127;
    int w = threadIdx.x & 127;
    int ch = threadIdx.x >> 7;

    const float* xb = x + b * (CC * HWSZ) + ch * 32 * HWSZ;
    const float* wr = woff_t + ch * 32 * 9 * 24;

    float acc[18];
    #pragma unroll
    for (int j = 0; j < 18; ++j) acc[j] = 0.f;

    for (int c = 0; c < 32; ++c) {
        const float* xc = xb + c * HWSZ;
        #pragma unroll
        for (int r = 0; r < 9; ++r) {
            int ry = r / 3 - 1, rx = r - (r / 3) * 3 - 1;
            int yy = h + ry, xx = w + rx;
            float xv = 0.f;
            if ((unsigned)yy < HH && (unsigned)xx < WW) xv = xc[yy * WW + xx];
            const float* wrow = wr + (c * 9 + r) * 24;
            #pragma unroll
            for (int q = 0; q < 4; ++q) {
                float4 wv = *(const float4*)(wrow + q * 4);
                acc[q*4+0] += xv * wv.x;
                acc[q*4+1] += xv * wv.y;
                acc[q*4+2] += xv * wv.z;
                acc[q*4+3] += xv * wv.w;
            }
            float2 wv2 = *(const float2*)(wrow + 16);
            acc[16] += xv * wv2.x;
            acc[17] += xv * wv2.y;
        }
    }

    if (ch == 1) {
        #pragma unroll
        for (int j = 0; j < 18; ++j) ex[w * 18 + j] = acc[j];
    }
    __syncthreads();
    if (ch == 0) {
        float* ob = off + b * (18 * HWSZ) + h * WW + w;
        #pragma unroll
        for (int j = 0; j < 18; ++j) {
            float v = acc[j] + ex[w * 18 + j] + b_off[j];
            ob[j * HWSZ] = fminf(fmaxf(v, -1.f), 1.f);
        }
    }
}

// 256 threads: w = tid&127, half = tid>>7 picks o-half (32 accs each).
// Bilinear data precomputed per kk into registers; c outer so each x slab
// is streamed exactly once per block.
__launch_bounds__(256)
__global__ void k_deform(const float* __restrict__ x,
                         const float* __restrict__ off,
                         const float* __restrict__ wdef_t,
                         const float* __restrict__ b_def,
                         float* __restrict__ out) {
    int sb = (blockIdx.x & 7) * 64 + (blockIdx.x >> 3);
    int b = sb >> 7, h = sb & 127;
    int w = threadIdx.x & 127;
    int half = threadIdx.x >> 7;
    int obase = half * 32;

    const float* xb = x + b * (CC * HWSZ);
    const float* offb = off + b * (18 * HWSZ) + h * WW + w;

    float wt[9][4];
    int base[9], dxs[9], dyw[9];
    #pragma unroll
    for (int kk = 0; kk < 9; ++kk) {
        float dy = offb[(2 * kk) * HWSZ];
        float dx = offb[(2 * kk + 1) * HWSZ];
        int ky = kk / 3 - 1, kx = kk - (kk / 3) * 3 - 1;
        float py = (float)(h + ky) + dy;
        float px = (float)(w + kx) + dx;
        float y0f = floorf(py), x0f = floorf(px);
        float ly = py - y0f, lx = px - x0f;
        int y0 = (int)y0f, x0 = (int)x0f;
        float vy0 = ((unsigned)y0 < HH) ? 1.f : 0.f;
        float vy1 = ((unsigned)(y0 + 1) < HH) ? 1.f : 0.f;
        float vx0 = ((unsigned)x0 < WW) ? 1.f : 0.f;
        float vx1 = ((unsigned)(x0 + 1) < WW) ? 1.f : 0.f;
        wt[kk][0] = (1.f - ly) * (1.f - lx) * vy0 * vx0;
        wt[kk][1] = (1.f - ly) * lx * vy0 * vx1;
        wt[kk][2] = ly * (1.f - lx) * vy1 * vx0;
        wt[kk][3] = ly * lx * vy1 * vx1;
        int yc0 = min(max(y0, 0), HH - 1), yc1 = min(max(y0 + 1, 0), HH - 1);
        int xc0 = min(max(x0, 0), WW - 1), xc1 = min(max(x0 + 1, 0), WW - 1);
        base[kk] = yc0 * WW + xc0;
        dxs[kk] = xc1 - xc0;
        dyw[kk] = (yc1 - yc0) * WW;
    }

    float acc[32];
    #pragma unroll
    for (int i = 0; i < 32; ++i) acc[i] = 0.f;

    for (int c = 0; c < CC; ++c) {
        const float* xc = xb + c * HWSZ;
        float s[9];
        #pragma unroll
        for (int kk = 0; kk < 9; ++kk) {
            int i00 = base[kk];
            float v00 = xc[i00];
            float v01 = xc[i00 + dxs[kk]];
            float v10 = xc[i00 + dyw[kk]];
            float v11 = xc[i00 + dyw[kk] + dxs[kk]];
            s[kk] = v00 * wt[kk][0] + v01 * wt[kk][1] +
                    v10 * wt[kk][2] + v11 * wt[kk][3];
        }
        #pragma unroll
        for (int kk = 0; kk < 9; ++kk) {
            const float4* w4 = (const float4*)(wdef_t + (c * 9 + kk) * 64 + obase);
            #pragma unroll
            for (int q = 0; q < 8; ++q) {
                float4 wv = w4[q];
                acc[q*4+0] += s[kk] * wv.x;
                acc[q*4+1] += s[kk] * wv.y;
                acc[q*4+2] += s[kk] * wv.z;
                acc[q*4+3] += s[kk] * wv.w;
            }
        }
    }

    float* ob = out + b * (OO * HWSZ) + h * WW + w;
    #pragma unroll
    for (int i = 0; i < 32; ++i)
        ob[(obase + i) * HWSZ] = acc[i] + b_def[obase + i];
}

extern "C" void kernel_launch(void* const* d_in, const int* in_sizes, int n_in,
                              void* d_out, int out_size, void* d_ws, size_t ws_size,
                              hipStream_t stream) {
    const float* x     = (const float*)d_in[0];
    const float* w_off = (const float*)d_in[1];
    const float* b_off = (const float*)d_in[2];
    const float* w_def = (const float*)d_in[3];
    const float* b_def = (const float*)d_in[4];
    float* out = (float*)d_out;

    float* ws     = (float*)d_ws;
    float* off    = ws;                      // 1179648 floats
    float* wdef_t = ws + 1179648;            // 36864
    float* woff_t = ws + 1179648 + 36864;    // 13824

    k_transpose<<<198, 256, 0, stream>>>(w_off, w_def, woff_t, wdef_t);
    k_offconv<<<512, 256, 0, stream>>>(x, woff_t, b_off, off);
    k_deform<<<512, 256, 0, stream>>>(x, off, wdef_t, b_def, out);
}

// Round 3
// 165.572 us; speedup vs baseline: 3.4189x; 3.4189x over previous
//
#include <hip/hip_runtime.h>
#include <hip/hip_bf16.h>

typedef __attribute__((ext_vector_type(8))) __bf16 bf16x8;
typedef __attribute__((ext_vector_type(4))) float f32x4;

#define HWB (128*128)

// K layout: k = c*16 + kk, kk<9 real (kk 9..15 zero in weights AND samp).
// K' = 1024, chunk = 8 channels = 128 k = one LDS samp row.
// wdef_p: [k8=0..127][o=0..63][j=0..7] bf16  (k = k8*8+j)
// woff_p: [k8=0..127][o=0..31][j=0..7] bf16  (o>=18 zero)

__global__ void k_prep(const float* __restrict__ w_off,
                       const float* __restrict__ w_def,
                       __bf16* __restrict__ wdef_p,
                       __bf16* __restrict__ woff_p) {
    int i = blockIdx.x * 256 + threadIdx.x;
    if (i < 65536) {
        int j = i & 7, o = (i >> 3) & 63, k8 = i >> 9;
        int k = k8 * 8 + j, c = k >> 4, kk = k & 15;
        float v = (kk < 9) ? w_def[o * 576 + c * 9 + kk] : 0.f;
        wdef_p[i] = (__bf16)v;
    } else {
        int i2 = i - 65536;
        if (i2 < 32768) {
            int j = i2 & 7, o = (i2 >> 3) & 31, k8 = i2 >> 8;
            int k = k8 * 8 + j, c = k >> 4, r = k & 15;
            float v = (r < 9 && o < 18) ? w_off[o * 576 + c * 9 + r] : 0.f;
            woff_p[i2] = (__bf16)v;
        }
    }
}

// LDS samp[px][k_local]: 128 x 128 bf16 = 32 KB, granule (16B) XOR swizzle:
// elem(px, g, j) = px*128 + ((g ^ (px&7)) << 3) + j
__device__ __forceinline__ int samp_idx(int px, int g) {
    return px * 128 + ((g ^ (px & 7)) << 3);
}

__launch_bounds__(256)
__global__ void k_off(const float* __restrict__ x,
                      const __bf16* __restrict__ woff_p,
                      const float* __restrict__ b_off,
                      float* __restrict__ off) {
    __shared__ __bf16 samp[128 * 128];
    int sb = (blockIdx.x & 7) * 64 + (blockIdx.x >> 3);
    int b = sb >> 7, h = sb & 127;
    int tid = threadIdx.x;
    int px = tid & 127, chalf = tid >> 7;
    int wv = tid >> 6, lane = tid & 63;
    int l15 = lane & 15, l4 = lane >> 4;

    {   // zero LDS (pad slots must be finite; weights there are 0)
        f32x4 z = {0.f, 0.f, 0.f, 0.f};
        for (int g = tid; g < 2048; g += 256)
            reinterpret_cast<f32x4*>(samp)[g] = z;
    }

    f32x4 acc[2][2];
    f32x4 zz = {0.f, 0.f, 0.f, 0.f};
    acc[0][0] = zz; acc[0][1] = zz; acc[1][0] = zz; acc[1][1] = zz;

    __syncthreads();

    for (int chunk = 0; chunk < 8; ++chunk) {
        #pragma unroll
        for (int cl = 0; cl < 4; ++cl) {
            int ci = chalf * 4 + cl;
            int c = chunk * 8 + ci;
            const float* xc = x + (size_t)(b * 64 + c) * HWB;
            __bf16 sv[9];
            #pragma unroll
            for (int r = 0; r < 9; ++r) {
                int yy = h + r / 3 - 1, xx = px + (r % 3) - 1;
                float v = 0.f;
                if ((unsigned)yy < 128u && (unsigned)xx < 128u)
                    v = xc[yy * 128 + xx];
                sv[r] = (__bf16)v;
            }
            bf16x8 pk;
            #pragma unroll
            for (int j = 0; j < 8; ++j) pk[j] = sv[j];
            *reinterpret_cast<bf16x8*>(&samp[samp_idx(px, ci * 2)]) = pk;
            samp[samp_idx(px, ci * 2 + 1)] = sv[8];
        }
        __syncthreads();

        #pragma unroll
        for (int ks = 0; ks < 4; ++ks) {
            int k8g = chunk * 16 + ks * 4 + l4;
            bf16x8 a0 = *reinterpret_cast<const bf16x8*>(woff_p + (k8g * 32 + l15) * 8);
            bf16x8 a1 = *reinterpret_cast<const bf16x8*>(woff_p + (k8g * 32 + 16 + l15) * 8);
            #pragma unroll
            for (int nt = 0; nt < 2; ++nt) {
                int pxn = (wv * 2 + nt) * 16 + l15;
                bf16x8 bf = *reinterpret_cast<const bf16x8*>(&samp[samp_idx(pxn, ks * 4 + l4)]);
                acc[0][nt] = __builtin_amdgcn_mfma_f32_16x16x32_bf16(a0, bf, acc[0][nt], 0, 0, 0);
                acc[1][nt] = __builtin_amdgcn_mfma_f32_16x16x32_bf16(a1, bf, acc[1][nt], 0, 0, 0);
            }
        }
        __syncthreads();
    }

    #pragma unroll
    for (int mt = 0; mt < 2; ++mt)
        #pragma unroll
        for (int nt = 0; nt < 2; ++nt)
            #pragma unroll
            for (int r = 0; r < 4; ++r) {
                int o = mt * 16 + l4 * 4 + r;
                if (o < 18) {
                    int pxn = (wv * 2 + nt) * 16 + l15;
                    float v = acc[mt][nt][r] + b_off[o];
                    v = fminf(fmaxf(v, -1.f), 1.f);
                    off[(size_t)(b * 18 + o) * HWB + h * 128 + pxn] = v;
                }
            }
}

__launch_bounds__(256)
__global__ void k_deform(const float* __restrict__ x,
                         const float* __restrict__ off,
                         const __bf16* __restrict__ wdef_p,
                         const float* __restrict__ b_def,
                         float* __restrict__ out) {
    __shared__ __bf16 samp[128 * 128];
    int sb = (blockIdx.x & 7) * 64 + (blockIdx.x >> 3);
    int b = sb >> 7, h = sb & 127;
    int tid = threadIdx.x;
    int px = tid & 127, chalf = tid >> 7;
    int wv = tid >> 6, lane = tid & 63;
    int l15 = lane & 15, l4 = lane >> 4;

    {
        f32x4 z = {0.f, 0.f, 0.f, 0.f};
        for (int g = tid; g < 2048; g += 256)
            reinterpret_cast<f32x4*>(samp)[g] = z;
    }

    // bilinear state per (px, kk): byte offsets
    const float* offb = off + (size_t)b * 18 * HWB + h * 128 + px;
    float wt[9][4];
    int base[9], dxs[9], dyw[9];
    #pragma unroll
    for (int kk = 0; kk < 9; ++kk) {
        float dy = offb[(2 * kk) * HWB];
        float dx = offb[(2 * kk + 1) * HWB];
        int ky = kk / 3 - 1, kx = kk - (kk / 3) * 3 - 1;
        float py = (float)(h + ky) + dy;
        float pxf = (float)(px + kx) + dx;
        float y0f = floorf(py), x0f = floorf(pxf);
        float ly = py - y0f, lx = pxf - x0f;
        int y0 = (int)y0f, x0 = (int)x0f;
        float vy0 = ((unsigned)y0 < 128u) ? 1.f : 0.f;
        float vy1 = ((unsigned)(y0 + 1) < 128u) ? 1.f : 0.f;
        float vx0 = ((unsigned)x0 < 128u) ? 1.f : 0.f;
        float vx1 = ((unsigned)(x0 + 1) < 128u) ? 1.f : 0.f;
        wt[kk][0] = (1.f - ly) * (1.f - lx) * vy0 * vx0;
        wt[kk][1] = (1.f - ly) * lx * vy0 * vx1;
        wt[kk][2] = ly * (1.f - lx) * vy1 * vx0;
        wt[kk][3] = ly * lx * vy1 * vx1;
        int yc0 = min(max(y0, 0), 127), yc1 = min(max(y0 + 1, 0), 127);
        int xc0 = min(max(x0, 0), 127), xc1 = min(max(x0 + 1, 0), 127);
        base[kk] = (yc0 * 128 + xc0) * 4;
        dxs[kk]  = (xc1 - xc0) * 4;
        dyw[kk]  = (yc1 - yc0) * 512;
    }

    f32x4 acc[2][4];
    f32x4 zz = {0.f, 0.f, 0.f, 0.f};
    #pragma unroll
    for (int mi = 0; mi < 2; ++mi)
        #pragma unroll
        for (int nt = 0; nt < 4; ++nt) acc[mi][nt] = zz;

    __syncthreads();

    for (int chunk = 0; chunk < 8; ++chunk) {
        #pragma unroll
        for (int cl = 0; cl < 4; ++cl) {
            int ci = chalf * 4 + cl;
            int c = chunk * 8 + ci;
            const char* xc = (const char*)x + ((size_t)(b * 64 + c) << 16);
            __bf16 sv[9];
            #pragma unroll
            for (int kk = 0; kk < 9; ++kk) {
                const char* p = xc + base[kk];
                float v00 = *(const float*)(p);
                float v01 = *(const float*)(p + dxs[kk]);
                float v10 = *(const float*)(p + dyw[kk]);
                float v11 = *(const float*)(p + dyw[kk] + dxs[kk]);
                float s = v00 * wt[kk][0] + v01 * wt[kk][1] +
                          v10 * wt[kk][2] + v11 * wt[kk][3];
                sv[kk] = (__bf16)s;
            }
            bf16x8 pk;
            #pragma unroll
            for (int j = 0; j < 8; ++j) pk[j] = sv[j];
            *reinterpret_cast<bf16x8*>(&samp[samp_idx(px, ci * 2)]) = pk;
            samp[samp_idx(px, ci * 2 + 1)] = sv[8];
        }
        __syncthreads();

        int m0 = (wv & 1) * 2;
        #pragma unroll
        for (int ks = 0; ks < 4; ++ks) {
            int k8g = chunk * 16 + ks * 4 + l4;
            bf16x8 a0 = *reinterpret_cast<const bf16x8*>(wdef_p + (k8g * 64 + m0 * 16 + l15) * 8);
            bf16x8 a1 = *reinterpret_cast<const bf16x8*>(wdef_p + (k8g * 64 + (m0 + 1) * 16 + l15) * 8);
            #pragma unroll
            for (int nt = 0; nt < 4; ++nt) {
                int pxn = ((wv >> 1) * 4 + nt) * 16 + l15;
                bf16x8 bf = *reinterpret_cast<const bf16x8*>(&samp[samp_idx(pxn, ks * 4 + l4)]);
                acc[0][nt] = __builtin_amdgcn_mfma_f32_16x16x32_bf16(a0, bf, acc[0][nt], 0, 0, 0);
                acc[1][nt] = __builtin_amdgcn_mfma_f32_16x16x32_bf16(a1, bf, acc[1][nt], 0, 0, 0);
            }
        }
        __syncthreads();
    }

    int m0 = (wv & 1) * 2;
    #pragma unroll
    for (int mi = 0; mi < 2; ++mi)
        #pragma unroll
        for (int nt = 0; nt < 4; ++nt)
            #pragma unroll
            for (int r = 0; r < 4; ++r) {
                int o = (m0 + mi) * 16 + l4 * 4 + r;
                int pxn = ((wv >> 1) * 4 + nt) * 16 + l15;
                out[(size_t)(b * 64 + o) * HWB + h * 128 + pxn] = acc[mi][nt][r] + b_def[o];
            }
}

extern "C" void kernel_launch(void* const* d_in, const int* in_sizes, int n_in,
                              void* d_out, int out_size, void* d_ws, size_t ws_size,
                              hipStream_t stream) {
    const float* x     = (const float*)d_in[0];
    const float* w_off = (const float*)d_in[1];
    const float* b_off = (const float*)d_in[2];
    const float* w_def = (const float*)d_in[3];
    const float* b_def = (const float*)d_in[4];
    float* out = (float*)d_out;

    char* wsb = (char*)d_ws;
    float*  off    = (float*)wsb;                         // 4,718,592 B
    __bf16* wdef_p = (__bf16*)(wsb + 4718592);            // 131,072 B
    __bf16* woff_p = (__bf16*)(wsb + 4718592 + 131072);   // 65,536 B

    k_prep<<<384, 256, 0, stream>>>(w_off, w_def, wdef_p, woff_p);
    k_off<<<512, 256, 0, stream>>>(x, woff_p, b_off, off);
    k_deform<<<512, 256, 0, stream>>>(x, off, wdef_p, b_def, out);
}

// Round 4
// 121.746 us; speedup vs baseline: 4.6496x; 1.3600x over previous
//
#include <hip/hip_runtime.h>
#include <hip/hip_bf16.h>

typedef __attribute__((ext_vector_type(8))) __bf16 bf16x8;
typedef __attribute__((ext_vector_type(4))) float f32x4;

#define HWB 16384

// K layout (both GEMMs): k = kk*64 + c, 18 k-steps of 32 (chalf in {0,1}).
// A-frag packs: lane l of k-step t, M-tile m holds W[o = m*16 + (l&15)]
//               [c = (t&1)*32 + (l>>4)*8 + j], kk = t>>1.
// wdef_ap: [t(18)][m(4)][lane(64)][j(8)] bf16 = 73728 B
// woff_ap: [t(18)][m(2)][lane(64)][j(8)] bf16 = 36864 B (o>=18 zero)

__global__ void k_prep(const float* __restrict__ w_off,
                       const float* __restrict__ w_def,
                       __bf16* __restrict__ wdef_ap,
                       __bf16* __restrict__ woff_ap) {
    int i = blockIdx.x * 256 + threadIdx.x;
    if (i < 36864) {
        int j = i & 7, l = (i >> 3) & 63, m = (i >> 9) & 3, t = i >> 11;
        int kk = t >> 1, ch = t & 1;
        int o = m * 16 + (l & 15);
        int c = ch * 32 + (l >> 4) * 8 + j;
        wdef_ap[i] = (__bf16)w_def[o * 576 + c * 9 + kk];
    } else if (i < 36864 + 18432) {
        int i2 = i - 36864;
        int j = i2 & 7, l = (i2 >> 3) & 63, m = (i2 >> 9) & 1, t = i2 >> 10;
        int kk = t >> 1, ch = t & 1;
        int o = m * 16 + (l & 15);
        int c = ch * 32 + (l >> 4) * 8 + j;
        woff_ap[i2] = (__bf16)((o < 18) ? w_off[o * 576 + c * 9 + kk] : 0.f);
    }
}

__launch_bounds__(256)
__global__ void k_fused(const float* __restrict__ x,
                        const __bf16* __restrict__ woff_ap,
                        const float* __restrict__ b_off,
                        const __bf16* __restrict__ wdef_ap,
                        const float* __restrict__ b_def,
                        float* __restrict__ out) {
    __shared__ float offsm[18 * 65];             // [o][px_in_block], padded

    int bid = blockIdx.x;
    int sb = (bid & 7) * 128 + (bid >> 3);       // bijective XCD swizzle
    int b = sb >> 8, h = (sb >> 1) & 127, half = sb & 1;
    int tid = threadIdx.x;
    int lane = tid & 63, wv = tid >> 6;
    int l15 = lane & 15, g = lane >> 4;
    int pxl = wv * 16 + l15;                     // px within block's 64
    int pxb = half * 64 + pxl;                   // global col

    const float* xb = x + (size_t)b * 64 * HWB;  // uniform base
    unsigned vg = (unsigned)(g * 8 * HWB);       // lane-group channel offset

    // ---------------- phase 0: 3x3 offset conv (O'=32, real 18) ----------
    f32x4 oacc[2];
    {
        f32x4 z = {0.f, 0.f, 0.f, 0.f};
        oacc[0] = z; oacc[1] = z;
    }
    for (int kk = 0; kk < 9; ++kk) {
        int ky = kk / 3 - 1, kx = kk - (kk / 3) * 3 - 1;
        int yy = h + ky;
        int xx = pxb + kx;
        bool valid = ((unsigned)yy < 128u) && ((unsigned)xx < 128u);
        int yyc = min(max(yy, 0), 127), xxc = min(max(xx, 0), 127);
        unsigned ib = (unsigned)(yyc * 128 + xxc) + vg;
        #pragma unroll
        for (int ch = 0; ch < 2; ++ch) {
            int t = kk * 2 + ch;
            float s[8];
            #pragma unroll
            for (int j = 0; j < 8; ++j) {
                float v = xb[ib + (unsigned)((ch * 32 + j) * HWB)];
                s[j] = valid ? v : 0.f;
            }
            bf16x8 B;
            #pragma unroll
            for (int j = 0; j < 8; ++j) B[j] = (__bf16)s[j];
            #pragma unroll
            for (int m = 0; m < 2; ++m) {
                bf16x8 A = *(const bf16x8*)(woff_ap + ((size_t)(t * 2 + m) * 64 + lane) * 8);
                oacc[m] = __builtin_amdgcn_mfma_f32_16x16x32_bf16(A, B, oacc[m], 0, 0, 0);
            }
        }
    }
    #pragma unroll
    for (int m = 0; m < 2; ++m)
        #pragma unroll
        for (int r = 0; r < 4; ++r) {
            int o = m * 16 + g * 4 + r;
            if (o < 18) {
                float v = oacc[m][r] + b_off[o];
                offsm[o * 65 + pxl] = fminf(fmaxf(v, -1.f), 1.f);
            }
        }
    __syncthreads();

    // ---------------- phase 1: deformable conv (O=64) --------------------
    f32x4 acc[4];
    {
        f32x4 z = {0.f, 0.f, 0.f, 0.f};
        acc[0] = z; acc[1] = z; acc[2] = z; acc[3] = z;
    }
    for (int kk = 0; kk < 9; ++kk) {
        float dy = offsm[(2 * kk) * 65 + pxl];
        float dx = offsm[(2 * kk + 1) * 65 + pxl];
        int ky = kk / 3 - 1, kx = kk - (kk / 3) * 3 - 1;
        float py = (float)(h + ky) + dy;
        float pxf = (float)(pxb + kx) + dx;
        float y0f = floorf(py), x0f = floorf(pxf);
        float ly = py - y0f, lx = pxf - x0f;
        int y0 = (int)y0f, x0 = (int)x0f;
        float vy0 = ((unsigned)y0 < 128u) ? 1.f : 0.f;
        float vy1 = ((unsigned)(y0 + 1) < 128u) ? 1.f : 0.f;
        float vx0 = ((unsigned)x0 < 128u) ? 1.f : 0.f;
        float vx1 = ((unsigned)(x0 + 1) < 128u) ? 1.f : 0.f;
        float w0 = (1.f - ly) * (1.f - lx) * vy0 * vx0;
        float w1 = (1.f - ly) * lx * vy0 * vx1;
        float w2 = ly * (1.f - lx) * vy1 * vx0;
        float w3 = ly * lx * vy1 * vx1;
        int yc0 = min(max(y0, 0), 127), yc1 = min(max(y0 + 1, 0), 127);
        int xc0 = min(max(x0, 0), 127), xc1 = min(max(x0 + 1, 0), 127);
        unsigned idx = (unsigned)(xc1 - xc0);          // 0 or 1
        unsigned idy = (unsigned)((yc1 - yc0) * 128);  // 0 or 128
        unsigned ib = (unsigned)(yc0 * 128 + xc0) + vg;

        #pragma unroll
        for (int ch = 0; ch < 2; ++ch) {
            int t = kk * 2 + ch;
            float s[8];
            #pragma unroll
            for (int j = 0; j < 8; ++j) {
                unsigned o0 = ib + (unsigned)((ch * 32 + j) * HWB);
                float v00 = xb[o0];
                float v01 = xb[o0 + idx];
                float v10 = xb[o0 + idy];
                float v11 = xb[o0 + idy + idx];
                s[j] = v00 * w0 + v01 * w1 + v10 * w2 + v11 * w3;
            }
            bf16x8 B;
            #pragma unroll
            for (int j = 0; j < 8; ++j) B[j] = (__bf16)s[j];
            #pragma unroll
            for (int m = 0; m < 4; ++m) {
                bf16x8 A = *(const bf16x8*)(wdef_ap + ((size_t)(t * 4 + m) * 64 + lane) * 8);
                acc[m] = __builtin_amdgcn_mfma_f32_16x16x32_bf16(A, B, acc[m], 0, 0, 0);
            }
        }
    }

    #pragma unroll
    for (int m = 0; m < 4; ++m)
        #pragma unroll
        for (int r = 0; r < 4; ++r) {
            int o = m * 16 + g * 4 + r;
            out[(size_t)(b * 64 + o) * HWB + h * 128 + pxb] = acc[m][r] + b_def[o];
        }
}

extern "C" void kernel_launch(void* const* d_in, const int* in_sizes, int n_in,
                              void* d_out, int out_size, void* d_ws, size_t ws_size,
                              hipStream_t stream) {
    const float* x     = (const float*)d_in[0];
    const float* w_off = (const float*)d_in[1];
    const float* b_off = (const float*)d_in[2];
    const float* w_def = (const float*)d_in[3];
    const float* b_def = (const float*)d_in[4];
    float* out = (float*)d_out;

    __bf16* wdef_ap = (__bf16*)d_ws;                      // 73728 B
    __bf16* woff_ap = (__bf16*)((char*)d_ws + 73728);     // 36864 B

    k_prep<<<216, 256, 0, stream>>>(w_off, w_def, wdef_ap, woff_ap);
    k_fused<<<1024, 256, 0, stream>>>(x, woff_ap, b_off, wdef_ap, b_def, out);
}

// Round 5
// 72.584 us; speedup vs baseline: 7.7989x; 1.6773x over previous
//
#include <hip/hip_runtime.h>
#include <hip/hip_bf16.h>

typedef __attribute__((ext_vector_type(8))) __bf16 bf16x8;
typedef __attribute__((ext_vector_type(4))) float f32x4;

#define HWB 16384

// K layout (both GEMMs): k = kk*64 + c, 18 k-steps of 32 (ch-half in {0,1}).
// A-frag packs: lane l of k-step t, M-tile m holds W[o = m*16 + (l&15)]
//               [c = (t&1)*32 + (l>>4)*8 + j], kk = t>>1.
// wdef_ap: [t(18)][m(4)][lane(64)][j(8)] bf16 = 73728 B
// woff_ap: [t(18)][m(2)][lane(64)][j(8)] bf16 = 36864 B (o>=18 zero)

__global__ void k_prep(const float* __restrict__ w_off,
                       const float* __restrict__ w_def,
                       __bf16* __restrict__ wdef_ap,
                       __bf16* __restrict__ woff_ap) {
    int i = blockIdx.x * 256 + threadIdx.x;
    if (i < 36864) {
        int j = i & 7, l = (i >> 3) & 63, m = (i >> 9) & 3, t = i >> 11;
        int kk = t >> 1, ch = t & 1;
        int o = m * 16 + (l & 15);
        int c = ch * 32 + (l >> 4) * 8 + j;
        wdef_ap[i] = (__bf16)w_def[o * 576 + c * 9 + kk];
    } else if (i < 36864 + 18432) {
        int i2 = i - 36864;
        int j = i2 & 7, l = (i2 >> 3) & 63, m = (i2 >> 9) & 1, t = i2 >> 10;
        int kk = t >> 1, ch = t & 1;
        int o = m * 16 + (l & 15);
        int c = ch * 32 + (l >> 4) * 8 + j;
        woff_ap[i2] = (__bf16)((o < 18) ? w_off[o * 576 + c * 9 + kk] : 0.f);
    }
}

// NCHW f32 -> NHWC bf16. One thread per pixel; reads coalesced along hw,
// writes one contiguous 128B channel-row per lane.
__global__ void k_xpose(const float* __restrict__ x, __bf16* __restrict__ xt) {
    int p = blockIdx.x * 256 + threadIdx.x;
    int b = p >> 14, hw = p & 16383;
    const float* xb = x + (size_t)b * 64 * HWB + hw;
    bf16x8 r[8];
    #pragma unroll
    for (int c = 0; c < 64; ++c) r[c >> 3][c & 7] = (__bf16)xb[(size_t)c * HWB];
    __bf16* ob = xt + (size_t)p * 64;
    #pragma unroll
    for (int q = 0; q < 8; ++q) *(bf16x8*)(ob + q * 8) = r[q];
}

__launch_bounds__(256)
__global__ void k_fused(const __bf16* __restrict__ xt,   // NHWC bf16 slice
                        const __bf16* __restrict__ woff_ap,
                        const float* __restrict__ b_off,
                        const __bf16* __restrict__ wdef_ap,
                        const float* __restrict__ b_def,
                        float* __restrict__ out, int bstart) {
    __shared__ float offsm[18 * 65];             // [o][px_in_block]

    int nwg = gridDim.x;
    int bid = blockIdx.x;
    int sb = (bid & 7) * (nwg >> 3) + (bid >> 3);   // bijective XCD swizzle
    int bl = sb >> 8, h = (sb >> 1) & 127, half = sb & 1;
    int b = bstart + bl;
    int tid = threadIdx.x;
    int lane = tid & 63, wv = tid >> 6;
    int l15 = lane & 15, g = lane >> 4;
    int pxl = wv * 16 + l15;                     // px within block's 64
    int pxb = half * 64 + pxl;                   // global col

    const __bf16* xb = xt + (size_t)bl * HWB * 64;
    unsigned cg = (unsigned)(g * 8);             // lane-group channel offset

    // ---------------- phase 0: 3x3 offset conv (O'=32, real 18) ----------
    f32x4 oacc[2];
    {
        f32x4 z = {0.f, 0.f, 0.f, 0.f};
        oacc[0] = z; oacc[1] = z;
    }
    bf16x8 zb = {};
    for (int kk = 0; kk < 9; ++kk) {
        int ky = kk / 3 - 1, kx = kk - (kk / 3) * 3 - 1;
        int yy = h + ky;
        int xx = pxb + kx;
        bool valid = ((unsigned)yy < 128u) && ((unsigned)xx < 128u);
        int yyc = min(max(yy, 0), 127), xxc = min(max(xx, 0), 127);
        unsigned ab = (unsigned)(yyc * 128 + xxc) * 64u + cg;
        #pragma unroll
        for (int ch = 0; ch < 2; ++ch) {
            int t = kk * 2 + ch;
            bf16x8 B = *(const bf16x8*)(xb + ab + (unsigned)(ch * 32));
            B = valid ? B : zb;
            #pragma unroll
            for (int m = 0; m < 2; ++m) {
                bf16x8 A = *(const bf16x8*)(woff_ap + ((size_t)(t * 2 + m) * 64 + lane) * 8);
                oacc[m] = __builtin_amdgcn_mfma_f32_16x16x32_bf16(A, B, oacc[m], 0, 0, 0);
            }
        }
    }
    #pragma unroll
    for (int m = 0; m < 2; ++m)
        #pragma unroll
        for (int r = 0; r < 4; ++r) {
            int o = m * 16 + g * 4 + r;
            if (o < 18) {
                float v = oacc[m][r] + b_off[o];
                offsm[o * 65 + pxl] = fminf(fmaxf(v, -1.f), 1.f);
            }
        }
    __syncthreads();

    // ---------------- phase 1: deformable conv (O=64) --------------------
    f32x4 acc[4];
    {
        f32x4 z = {0.f, 0.f, 0.f, 0.f};
        acc[0] = z; acc[1] = z; acc[2] = z; acc[3] = z;
    }
    for (int kk = 0; kk < 9; ++kk) {
        float dy = offsm[(2 * kk) * 65 + pxl];
        float dx = offsm[(2 * kk + 1) * 65 + pxl];
        int ky = kk / 3 - 1, kx = kk - (kk / 3) * 3 - 1;
        float py = (float)(h + ky) + dy;
        float pxf = (float)(pxb + kx) + dx;
        float y0f = floorf(py), x0f = floorf(pxf);
        float ly = py - y0f, lx = pxf - x0f;
        int y0 = (int)y0f, x0 = (int)x0f;
        float vy0 = ((unsigned)y0 < 128u) ? 1.f : 0.f;
        float vy1 = ((unsigned)(y0 + 1) < 128u) ? 1.f : 0.f;
        float vx0 = ((unsigned)x0 < 128u) ? 1.f : 0.f;
        float vx1 = ((unsigned)(x0 + 1) < 128u) ? 1.f : 0.f;
        float w0 = (1.f - ly) * (1.f - lx) * vy0 * vx0;
        float w1 = (1.f - ly) * lx * vy0 * vx1;
        float w2 = ly * (1.f - lx) * vy1 * vx0;
        float w3 = ly * lx * vy1 * vx1;
        int yc0 = min(max(y0, 0), 127), yc1 = min(max(y0 + 1, 0), 127);
        int xc0 = min(max(x0, 0), 127), xc1 = min(max(x0 + 1, 0), 127);
        unsigned a00 = (unsigned)(yc0 * 128 + xc0) * 64u + cg;
        unsigned adx = (unsigned)(xc1 - xc0) * 64u;      // 0 or 64
        unsigned ady = (unsigned)(yc1 - yc0) * 8192u;    // 0 or 128*64

        #pragma unroll
        for (int ch = 0; ch < 2; ++ch) {
            int t = kk * 2 + ch;
            unsigned ab = a00 + (unsigned)(ch * 32);
            bf16x8 c00 = *(const bf16x8*)(xb + ab);
            bf16x8 c01 = *(const bf16x8*)(xb + ab + adx);
            bf16x8 c10 = *(const bf16x8*)(xb + ab + ady);
            bf16x8 c11 = *(const bf16x8*)(xb + ab + ady + adx);
            bf16x8 B;
            #pragma unroll
            for (int j = 0; j < 8; ++j) {
                float s = w0 * (float)c00[j] + w1 * (float)c01[j] +
                          w2 * (float)c10[j] + w3 * (float)c11[j];
                B[j] = (__bf16)s;
            }
            #pragma unroll
            for (int m = 0; m < 4; ++m) {
                bf16x8 A = *(const bf16x8*)(wdef_ap + ((size_t)(t * 4 + m) * 64 + lane) * 8);
                acc[m] = __builtin_amdgcn_mfma_f32_16x16x32_bf16(A, B, acc[m], 0, 0, 0);
            }
        }
    }

    #pragma unroll
    for (int m = 0; m < 4; ++m)
        #pragma unroll
        for (int r = 0; r < 4; ++r) {
            int o = m * 16 + g * 4 + r;
            out[(size_t)(b * 64 + o) * HWB + h * 128 + pxb] = acc[m][r] + b_def[o];
        }
}

extern "C" void kernel_launch(void* const* d_in, const int* in_sizes, int n_in,
                              void* d_out, int out_size, void* d_ws, size_t ws_size,
                              hipStream_t stream) {
    const float* x     = (const float*)d_in[0];
    const float* w_off = (const float*)d_in[1];
    const float* b_off = (const float*)d_in[2];
    const float* w_def = (const float*)d_in[3];
    const float* b_def = (const float*)d_in[4];
    float* out = (float*)d_out;

    char* wsb = (char*)d_ws;
    __bf16* wdef_ap = (__bf16*)wsb;                    // 73728 B
    __bf16* woff_ap = (__bf16*)(wsb + 73728);          // 36864 B
    __bf16* xt      = (__bf16*)(wsb + 110592);         // NHWC bf16

    k_prep<<<216, 256, 0, stream>>>(w_off, w_def, wdef_ap, woff_ap);

    if (ws_size >= (size_t)110592 + 8388608) {
        // single shot: all 4 batches transposed (8.4 MB)
        k_xpose<<<256, 256, 0, stream>>>(x, xt);
        k_fused<<<1024, 256, 0, stream>>>(xt, woff_ap, b_off, wdef_ap, b_def, out, 0);
    } else {
        // batch-sliced fallback (2.1 MB slice, stream-ordered)
        for (int b = 0; b < 4; ++b) {
            k_xpose<<<64, 256, 0, stream>>>(x + (size_t)b * 64 * HWB, xt);
            k_fused<<<256, 256, 0, stream>>>(xt, woff_ap, b_off, wdef_ap, b_def, out, b);
        }
    }
}

// Round 6
// 72.216 us; speedup vs baseline: 7.8385x; 1.0051x over previous
//
#include <hip/hip_runtime.h>

typedef _Float16 f16;
typedef __attribute__((ext_vector_type(8))) _Float16 f16x8;
typedef __attribute__((ext_vector_type(4))) float f32x4;

#define HWB 16384

// K layout (both GEMMs): k = kk*64 + c, 18 k-steps of 32 (ch-half in {0,1}).
// A-frag packs: lane l of k-step t, M-tile m holds W[o = m*16 + (l&15)]
//               [c = (t&1)*32 + (l>>4)*8 + j], kk = t>>1.
// wdef_ap: [t(18)][m(4)][lane(64)][j(8)] f16 = 73728 B
// woff_ap: [t(18)][m(2)][lane(64)][j(8)] f16 = 36864 B (o>=18 zero)

__global__ void k_prep(const float* __restrict__ w_off,
                       const float* __restrict__ w_def,
                       f16* __restrict__ wdef_ap,
                       f16* __restrict__ woff_ap) {
    int i = blockIdx.x * 256 + threadIdx.x;
    if (i < 36864) {
        int j = i & 7, l = (i >> 3) & 63, m = (i >> 9) & 3, t = i >> 11;
        int kk = t >> 1, ch = t & 1;
        int o = m * 16 + (l & 15);
        int c = ch * 32 + (l >> 4) * 8 + j;
        wdef_ap[i] = (f16)w_def[o * 576 + c * 9 + kk];
    } else if (i < 36864 + 18432) {
        int i2 = i - 36864;
        int j = i2 & 7, l = (i2 >> 3) & 63, m = (i2 >> 9) & 1, t = i2 >> 10;
        int kk = t >> 1, ch = t & 1;
        int o = m * 16 + (l & 15);
        int c = ch * 32 + (l >> 4) * 8 + j;
        woff_ap[i2] = (f16)((o < 18) ? w_off[o * 576 + c * 9 + kk] : 0.f);
    }
}

// NCHW f32 -> NHWC f16. One thread per pixel; reads coalesced along hw,
// writes one contiguous 128B channel-row per lane.
__global__ void k_xpose(const float* __restrict__ x, f16* __restrict__ xt) {
    int p = blockIdx.x * 256 + threadIdx.x;
    int b = p >> 14, hw = p & 16383;
    const float* xb = x + (size_t)b * 64 * HWB + hw;
    f16x8 r[8];
    #pragma unroll
    for (int c = 0; c < 64; ++c) r[c >> 3][c & 7] = (f16)xb[(size_t)c * HWB];
    f16* ob = xt + (size_t)p * 64;
    #pragma unroll
    for (int q = 0; q < 8; ++q) *(f16x8*)(ob + q * 8) = r[q];
}

__launch_bounds__(256, 4)
__global__ void k_fused(const f16* __restrict__ xt,      // NHWC f16 slice
                        const f16* __restrict__ woff_ap,
                        const float* __restrict__ b_off,
                        const f16* __restrict__ wdef_ap,
                        const float* __restrict__ b_def,
                        float* __restrict__ out, int bstart) {
    __shared__ float offsm[18 * 65];             // [o][px_in_block]

    int nwg = gridDim.x;
    int bid = blockIdx.x;
    int sb = (bid & 7) * (nwg >> 3) + (bid >> 3);   // bijective XCD swizzle
    int bl = sb >> 8, h = (sb >> 1) & 127, half = sb & 1;
    int b = bstart + bl;
    int tid = threadIdx.x;
    int lane = tid & 63, wv = tid >> 6;
    int l15 = lane & 15, g = lane >> 4;
    int pxl = wv * 16 + l15;                     // px within block's 64
    int pxb = half * 64 + pxl;                   // global col

    const f16* xb = xt + (size_t)bl * HWB * 64;
    unsigned cg = (unsigned)(g * 8);             // lane-group channel offset

    // ---------------- phase 0: 3x3 offset conv (O'=32, real 18) ----------
    f32x4 oacc[2];
    {
        f32x4 z = {0.f, 0.f, 0.f, 0.f};
        oacc[0] = z; oacc[1] = z;
    }
    f16x8 zb = {};
    #pragma unroll
    for (int kk = 0; kk < 9; ++kk) {
        int ky = kk / 3 - 1, kx = kk - (kk / 3) * 3 - 1;
        int yy = h + ky;
        int xx = pxb + kx;
        bool valid = ((unsigned)yy < 128u) && ((unsigned)xx < 128u);
        int yyc = min(max(yy, 0), 127), xxc = min(max(xx, 0), 127);
        unsigned ab = (unsigned)(yyc * 128 + xxc) * 64u + cg;
        #pragma unroll
        for (int ch = 0; ch < 2; ++ch) {
            int t = kk * 2 + ch;
            f16x8 B = *(const f16x8*)(xb + ab + (unsigned)(ch * 32));
            B = valid ? B : zb;
            #pragma unroll
            for (int m = 0; m < 2; ++m) {
                f16x8 A = *(const f16x8*)(woff_ap + ((size_t)(t * 2 + m) * 64 + lane) * 8);
                oacc[m] = __builtin_amdgcn_mfma_f32_16x16x32_f16(A, B, oacc[m], 0, 0, 0);
            }
        }
    }
    #pragma unroll
    for (int m = 0; m < 2; ++m)
        #pragma unroll
        for (int r = 0; r < 4; ++r) {
            int o = m * 16 + g * 4 + r;
            if (o < 18) {
                float v = oacc[m][r] + b_off[o];
                offsm[o * 65 + pxl] = fminf(fmaxf(v, -1.f), 1.f);
            }
        }
    __syncthreads();

    // ---------------- phase 1: deformable conv (O=64) --------------------
    f32x4 acc[4];
    {
        f32x4 z = {0.f, 0.f, 0.f, 0.f};
        acc[0] = z; acc[1] = z; acc[2] = z; acc[3] = z;
    }
    #pragma unroll
    for (int kk = 0; kk < 9; ++kk) {
        float dy = offsm[(2 * kk) * 65 + pxl];
        float dx = offsm[(2 * kk + 1) * 65 + pxl];
        int ky = kk / 3 - 1, kx = kk - (kk / 3) * 3 - 1;
        float py = (float)(h + ky) + dy;
        float pxf = (float)(pxb + kx) + dx;
        float y0f = floorf(py), x0f = floorf(pxf);
        float ly = py - y0f, lx = pxf - x0f;
        int y0 = (int)y0f, x0 = (int)x0f;
        float vy0 = ((unsigned)y0 < 128u) ? 1.f : 0.f;
        float vy1 = ((unsigned)(y0 + 1) < 128u) ? 1.f : 0.f;
        float vx0 = ((unsigned)x0 < 128u) ? 1.f : 0.f;
        float vx1 = ((unsigned)(x0 + 1) < 128u) ? 1.f : 0.f;
        f16 w0 = (f16)((1.f - ly) * (1.f - lx) * vy0 * vx0);
        f16 w1 = (f16)((1.f - ly) * lx * vy0 * vx1);
        f16 w2 = (f16)(ly * (1.f - lx) * vy1 * vx0);
        f16 w3 = (f16)(ly * lx * vy1 * vx1);
        int yc0 = min(max(y0, 0), 127), yc1 = min(max(y0 + 1, 0), 127);
        int xc0 = min(max(x0, 0), 127), xc1 = min(max(x0 + 1, 0), 127);
        unsigned a00 = (unsigned)(yc0 * 128 + xc0) * 64u + cg;
        unsigned adx = (unsigned)(xc1 - xc0) * 64u;      // 0 or 64
        unsigned ady = (unsigned)(yc1 - yc0) * 8192u;    // 0 or 128*64

        #pragma unroll
        for (int ch = 0; ch < 2; ++ch) {
            int t = kk * 2 + ch;
            unsigned ab = a00 + (unsigned)(ch * 32);
            f16x8 c00 = *(const f16x8*)(xb + ab);
            f16x8 c01 = *(const f16x8*)(xb + ab + adx);
            f16x8 c10 = *(const f16x8*)(xb + ab + ady);
            f16x8 c11 = *(const f16x8*)(xb + ab + ady + adx);
            // packed f16 bilinear: 16 v_pk_fma_f16, no scalar converts
            f16x8 B = c00 * w0 + c01 * w1 + c10 * w2 + c11 * w3;
            #pragma unroll
            for (int m = 0; m < 4; ++m) {
                f16x8 A = *(const f16x8*)(wdef_ap + ((size_t)(t * 4 + m) * 64 + lane) * 8);
                acc[m] = __builtin_amdgcn_mfma_f32_16x16x32_f16(A, B, acc[m], 0, 0, 0);
            }
        }
    }

    #pragma unroll
    for (int m = 0; m < 4; ++m)
        #pragma unroll
        for (int r = 0; r < 4; ++r) {
            int o = m * 16 + g * 4 + r;
            out[(size_t)(b * 64 + o) * HWB + h * 128 + pxb] = acc[m][r] + b_def[o];
        }
}

extern "C" void kernel_launch(void* const* d_in, const int* in_sizes, int n_in,
                              void* d_out, int out_size, void* d_ws, size_t ws_size,
                              hipStream_t stream) {
    const float* x     = (const float*)d_in[0];
    const float* w_off = (const float*)d_in[1];
    const float* b_off = (const float*)d_in[2];
    const float* w_def = (const float*)d_in[3];
    const float* b_def = (const float*)d_in[4];
    float* out = (float*)d_out;

    char* wsb = (char*)d_ws;
    f16* wdef_ap = (f16*)wsb;                    // 73728 B
    f16* woff_ap = (f16*)(wsb + 73728);          // 36864 B
    f16* xt      = (f16*)(wsb + 110592);         // NHWC f16

    k_prep<<<216, 256, 0, stream>>>(w_off, w_def, wdef_ap, woff_ap);

    if (ws_size >= (size_t)110592 + 8388608) {
        // single shot: all 4 batches transposed (8.4 MB)
        k_xpose<<<256, 256, 0, stream>>>(x, xt);
        k_fused<<<1024, 256, 0, stream>>>(xt, woff_ap, b_off, wdef_ap, b_def, out, 0);
    } else {
        // batch-sliced fallback (2.1 MB slice, stream-ordered)
        for (int b = 0; b < 4; ++b) {
            k_xpose<<<64, 256, 0, stream>>>(x + (size_t)b * 64 * HWB, xt);
            k_fused<<<256, 256, 0, stream>>>(xt, woff_ap, b_off, wdef_ap, b_def, out, b);
        }
    }
}